// Round 1
// baseline (1316.965 us; speedup 1.0000x reference)
//
#include <hip/hip_runtime.h>
#include <math.h>

// SO3 DiT layer, MI355X fp32 baseline.
// N=6000 nodes, E=72000 edges, P=2, L=2, M=9, F=64, H=4, DH=16, T=64, NF=256
// Strategy: no-LDS small GEMMs. Broadcast operands go through the scalar path
// (s_load on wave-uniform addresses), per-lane weight columns held in VGPRs.

#define NN 6000
#define EE 72000

__device__ __forceinline__ float wsum(float v) {
#pragma unroll
  for (int o = 32; o >= 1; o >>= 1) v += __shfl_xor(v, o, 64);
  return v;
}
__device__ __forceinline__ int deg_of(int m) { return (m == 0) ? 0 : ((m < 4) ? 1 : 2); }
// order-preserving float->uint for atomicMax-based segment max
__device__ __forceinline__ unsigned fenc(float x) {
  unsigned u = __float_as_uint(x);
  return (u & 0x80000000u) ? ~u : (u | 0x80000000u);
}
__device__ __forceinline__ float fdec(unsigned k) {
  unsigned u = (k & 0x80000000u) ? (k & 0x7fffffffu) : ~k;
  return __uint_as_float(u);
}

// ---------------- K1a: LayerNorm(T=64) + SiLU, one wave per node ----------------
__global__ __launch_bounds__(256) void k_ln_t(const float* __restrict__ ft,
                                              const float* __restrict__ lns,
                                              const float* __restrict__ lnb,
                                              float* __restrict__ sbuf) {
  int w = (blockIdx.x * 256 + threadIdx.x) >> 6;  // node, exact 6000
  int lane = threadIdx.x & 63;
  float t = ft[(size_t)w * 64 + lane];
  float mu = wsum(t) * (1.f / 64.f);
  float d = t - mu;
  float var = wsum(d * d) * (1.f / 64.f);
  float cin = d * rsqrtf(var + 1e-6f) * lns[lane] + lnb[lane];
  sbuf[(size_t)w * 64 + lane] = cin / (1.f + expf(-cin));
}

// ---------------- K1b: c = silu @ W_c + b_c  (64 -> 1664), 8 nodes/block ----------------
__global__ __launch_bounds__(256) void k_cond_mm(const float* __restrict__ sbuf,
                                                 const float* __restrict__ Wc,
                                                 const float* __restrict__ bc,
                                                 float* __restrict__ c) {
  int n0 = blockIdx.x * 8;  // 750 blocks
  for (int jj = threadIdx.x; jj < 1664; jj += 256) {
    float acc[8] = {0, 0, 0, 0, 0, 0, 0, 0};
#pragma unroll 8
    for (int k2 = 0; k2 < 64; k2++) {
      float wv = Wc[(size_t)k2 * 1664 + jj];
#pragma unroll
      for (int nd = 0; nd < 8; nd++) acc[nd] += sbuf[(size_t)(n0 + nd) * 64 + k2] * wv;
    }
    float b = bc[jj];
#pragma unroll
    for (int nd = 0; nd < 8; nd++) c[(size_t)(n0 + nd) * 1664 + jj] = acc[nd] + b;
  }
}

// ---------------- K2/K8: eqv layernorm + modulate, one wave per (n,p) ----------------
__global__ __launch_bounds__(256) void k_lnmod(const float* __restrict__ xin,
                                               const float* __restrict__ c,
                                               float* __restrict__ xout,
                                               int goff, int boff) {
  int w = (blockIdx.x * 256 + threadIdx.x) >> 6;  // (n,p) pair, exact 12000
  int lane = threadIdx.x & 63;
  int n = w >> 1, p = w & 1;
  const float* xb = xin + (size_t)w * 576 + lane;
  float x0 = xb[0], x1 = xb[64], x2 = xb[128], x3 = xb[192], x4 = xb[256];
  float x5 = xb[320], x6 = xb[384], x7 = xb[448], x8 = xb[512];
  float mu = wsum(x0) * (1.f / 64.f);
  x0 -= mu;
  float n20 = x0 * x0;
  float n21 = (x1 * x1 + x2 * x2 + x3 * x3) * (1.f / 3.f);
  float n22 = (x4 * x4 + x5 * x5 + x6 * x6 + x7 * x7 + x8 * x8) * (1.f / 5.f);
  n20 = wsum(n20) * (1.f / 64.f);
  n21 = wsum(n21) * (1.f / 64.f);
  n22 = wsum(n22) * (1.f / 64.f);
  float i0 = rsqrtf(n20 + 1e-6f), i1 = rsqrtf(n21 + 1e-6f), i2 = rsqrtf(n22 + 1e-6f);
  const float* cb = c + (size_t)n * 1664;
  float g0 = 1.f + cb[goff + p * 192 + lane];
  float g1 = 1.f + cb[goff + p * 192 + 64 + lane];
  float g2 = 1.f + cb[goff + p * 192 + 128 + lane];
  float bsh = cb[boff + lane];
  float* ob = xout + (size_t)w * 576 + lane;
  ob[0] = x0 * i0 * g0 + bsh;
  ob[64] = x1 * i1 * g1;
  ob[128] = x2 * i1 * g1;
  ob[192] = x3 * i1 * g1;
  ob[256] = x4 * i2 * g2;
  ob[320] = x5 * i2 * g2;
  ob[384] = x6 * i2 * g2;
  ob[448] = x7 * i2 * g2;
  ob[512] = x8 * i2 * g2;
}

// ---------------- K3: per-(p,m) 64x64 projection, weight column in VGPRs ----------------
__global__ __launch_bounds__(256) void k_rowmat(const float* __restrict__ x,
                                                const float* __restrict__ W,
                                                float* __restrict__ out) {
  int pm = blockIdx.y;
  int p = pm / 9, mm = pm % 9, dm = deg_of(mm);
  int lane = threadIdx.x & 63;
  const float* Wb = W + (size_t)(p * 3 + dm) * 4096;
  float wreg[64];
#pragma unroll
  for (int f = 0; f < 64; f++) wreg[f] = Wb[f * 64 + lane];
  int wid = __builtin_amdgcn_readfirstlane((int)((blockIdx.x * 256 + threadIdx.x) >> 6));
  int nwaves = (gridDim.x * 256) >> 6;
  for (int n = wid; n < NN; n += nwaves) {
    const float* xr = x + ((size_t)n * 18 + pm) * 64;  // uniform -> s_load
    float acc = 0.f;
#pragma unroll
    for (int f = 0; f < 64; f++) acc += xr[f] * wreg[f];
    out[((size_t)n * 18 + pm) * 64 + lane] = acc;
  }
}

// ---------------- K4: edge logits + segment max + cnt/cutsum ----------------
__global__ __launch_bounds__(256) void k_logits(const float* __restrict__ fe,
                                                const float* __restrict__ Weqk,
                                                const float* __restrict__ q,
                                                const float* __restrict__ kk,
                                                const int* __restrict__ src_idx,
                                                const int* __restrict__ dst_idx,
                                                const float* __restrict__ cutoff,
                                                float* __restrict__ logits,
                                                unsigned* __restrict__ lmax,
                                                float* __restrict__ cnt,
                                                float* __restrict__ cutsum) {
  int lane = threadIdx.x & 63;
  float wreg[64];
#pragma unroll
  for (int f = 0; f < 64; f++) wreg[f] = Weqk[f * 64 + lane];
  int wid = __builtin_amdgcn_readfirstlane((int)((blockIdx.x * 256 + threadIdx.x) >> 6));
  int nw = (gridDim.x * 256) >> 6;
  for (int e = wid; e < EE; e += nw) {
    int src = __builtin_amdgcn_readfirstlane(src_idx[e]);
    int dst = __builtin_amdgcn_readfirstlane(dst_idx[e]);
    const float* feb = fe + (size_t)e * 576;  // uniform -> s_load
    const float* qb = q + (size_t)dst * 1152 + lane;
    const float* kb = kk + (size_t)src * 1152 + lane;
    float lacc = 0.f;
    for (int m = 0; m < 9; m++) {
      float eq = 0.f;
#pragma unroll
      for (int f = 0; f < 64; f++) eq += feb[m * 64 + f] * wreg[f];
      float qk = qb[m * 64] * kb[m * 64] + qb[m * 64 + 576] * kb[m * 64 + 576];
      lacc += eq * qk;
    }
    lacc *= 0.05892556509887896f;  // 1/sqrt(P*M*DH)=1/sqrt(288)
    lacc += __shfl_xor(lacc, 8, 64);
    lacc += __shfl_xor(lacc, 4, 64);
    lacc += __shfl_xor(lacc, 2, 64);
    lacc += __shfl_xor(lacc, 1, 64);
    if ((lane & 15) == 0) {
      int h = lane >> 4;
      logits[(size_t)e * 4 + h] = lacc;
      atomicMax(lmax + (size_t)dst * 4 + h, fenc(lacc));
    }
    if (lane == 0) {
      unsafeAtomicAdd(cnt + dst, 1.f);
      unsafeAtomicAdd(cutsum + dst, cutoff[e]);
    }
  }
}

// ---------------- K5: w = exp(logit - lmax)*cutoff, denom segment sum ----------------
__global__ __launch_bounds__(256) void k_expw(float* __restrict__ logw,
                                              const unsigned* __restrict__ lmax,
                                              const int* __restrict__ dst_idx,
                                              const float* __restrict__ cutoff,
                                              float* __restrict__ denom) {
  int t = blockIdx.x * 256 + threadIdx.x;  // exact E*4
  int e = t >> 2, h = t & 3;
  int dst = dst_idx[e];
  float wv = expf(logw[t] - fdec(lmax[(size_t)dst * 4 + h])) * cutoff[e];
  logw[t] = wv;
  unsafeAtomicAdd(denom + (size_t)dst * 4 + h, wv);
}

// ---------------- K6: e_v GEMM + attn-weighted scatter into attn_out ----------------
__global__ __launch_bounds__(256) void k_agg(const float* __restrict__ fe,
                                             const float* __restrict__ Wev,
                                             const float* __restrict__ v,
                                             const int* __restrict__ src_idx,
                                             const int* __restrict__ dst_idx,
                                             const float* __restrict__ w_ws,
                                             const float* __restrict__ denom,
                                             float* __restrict__ attn_out) {
  int lane = threadIdx.x & 63;
  int h4 = lane >> 4;
  float wreg[64];
#pragma unroll
  for (int f = 0; f < 64; f++) wreg[f] = Wev[f * 64 + lane];
  int wid = __builtin_amdgcn_readfirstlane((int)((blockIdx.x * 256 + threadIdx.x) >> 6));
  int nw = (gridDim.x * 256) >> 6;
  for (int e = wid; e < EE; e += nw) {
    int src = __builtin_amdgcn_readfirstlane(src_idx[e]);
    int dst = __builtin_amdgcn_readfirstlane(dst_idx[e]);
    const float* feb = fe + (size_t)e * 576;
    float attn = w_ws[(size_t)e * 4 + h4] / (denom[(size_t)dst * 4 + h4] + 1e-9f);
    const float* vb = v + (size_t)src * 1152 + lane;
    float* ob = attn_out + (size_t)dst * 1152 + lane;
    for (int m = 0; m < 9; m++) {
      float ev = 0.f;
#pragma unroll
      for (int f = 0; f < 64; f++) ev += feb[m * 64 + f] * wreg[f];
      float sc = attn * ev;
      unsafeAtomicAdd(ob + m * 64, sc * vb[m * 64]);
      unsafeAtomicAdd(ob + m * 64 + 576, sc * vb[m * 64 + 576]);
    }
  }
}

// ---------------- K7: Wo projection + post-select + gate(a1) + residual ----------------
__global__ __launch_bounds__(256) void k_wo_post(const float* __restrict__ attn_out,
                                                 const float* __restrict__ Wo,
                                                 const float* __restrict__ xpre,
                                                 const float* __restrict__ fnodes,
                                                 const float* __restrict__ c,
                                                 const float* __restrict__ cnt,
                                                 const float* __restrict__ cutsum,
                                                 float* __restrict__ out) {
  int pm = blockIdx.y;
  int p = pm / 9, mm = pm % 9, dm = deg_of(mm);
  int lane = threadIdx.x & 63;
  const float* Wb = Wo + (size_t)(p * 3 + dm) * 4096;
  float wreg[64];
#pragma unroll
  for (int f = 0; f < 64; f++) wreg[f] = Wb[f * 64 + lane];
  int wid = __builtin_amdgcn_readfirstlane((int)((blockIdx.x * 256 + threadIdx.x) >> 6));
  int nwaves = (gridDim.x * 256) >> 6;
  for (int n = wid; n < NN; n += nwaves) {
    const float* xr = attn_out + ((size_t)n * 18 + pm) * 64;
    float acc = 0.f;
#pragma unroll
    for (int f = 0; f < 64; f++) acc += xr[f] * wreg[f];
    float mc = cutsum[n] / fmaxf(cnt[n], 1.f);
    size_t idx = ((size_t)n * 18 + pm) * 64 + lane;
    float post = (mc < 1e-5f) ? xpre[idx] : acc;
    float a1v = c[(size_t)n * 1664 + 448 + (p * 3 + dm) * 64 + lane];
    out[idx] = fnodes[idx] + a1v * post;
  }
}

// ---------------- K9a: h = eqv_gelu(x_pre2 @ W1), 8 nodes/block ----------------
__global__ __launch_bounds__(256) void k_mlp1(const float* __restrict__ xp2,
                                              const float* __restrict__ W1,
                                              float* __restrict__ h) {
  int n0 = blockIdx.x * 8;  // 750 blocks
  int j = threadIdx.x;
  float gate[8];
  {  // pm = 0 first: its output defines the gelu gate per column
    float acc[8] = {0, 0, 0, 0, 0, 0, 0, 0};
#pragma unroll 8
    for (int f = 0; f < 64; f++) {
      float wv = W1[(size_t)f * 256 + j];
#pragma unroll
      for (int nd = 0; nd < 8; nd++) acc[nd] += xp2[(size_t)(n0 + nd) * 1152 + f] * wv;
    }
#pragma unroll
    for (int nd = 0; nd < 8; nd++) {
      float s = acc[nd];
      float g = (fabsf(s) > 1e-4f)
                    ? 0.5f * (1.f + tanhf(0.7978845608028654f * (s + 0.044715f * s * s * s)))
                    : 0.5f;
      gate[nd] = g;
      h[(size_t)(n0 + nd) * 4608 + j] = s * g;
    }
  }
  for (int pm = 1; pm < 18; pm++) {
    int p = pm / 9, mm = pm % 9, dm = deg_of(mm);
    const float* wb = W1 + (size_t)(p * 3 + dm) * 16384;
    float acc[8] = {0, 0, 0, 0, 0, 0, 0, 0};
#pragma unroll 8
    for (int f = 0; f < 64; f++) {
      float wv = wb[(size_t)f * 256 + j];
#pragma unroll
      for (int nd = 0; nd < 8; nd++)
        acc[nd] += xp2[(size_t)(n0 + nd) * 1152 + pm * 64 + f] * wv;
    }
#pragma unroll
    for (int nd = 0; nd < 8; nd++)
      h[(size_t)(n0 + nd) * 4608 + pm * 256 + j] = acc[nd] * gate[nd];
  }
}

// ---------------- K9b: out += a2 * (h @ W2), 8 nodes/block ----------------
__global__ __launch_bounds__(256) void k_mlp2(const float* __restrict__ h,
                                              const float* __restrict__ W2,
                                              const float* __restrict__ c,
                                              float* __restrict__ out) {
  int n0 = blockIdx.x * 8;  // 750 blocks
  int g = threadIdx.x & 63;
  int pr = threadIdx.x >> 6;
  for (int pm = pr; pm < 18; pm += 4) {
    int p = pm / 9, mm = pm % 9, dm = deg_of(mm);
    const float* wb = W2 + (size_t)(p * 3 + dm) * 16384;
    float acc[8] = {0, 0, 0, 0, 0, 0, 0, 0};
#pragma unroll 8
    for (int k = 0; k < 256; k++) {
      float wv = wb[(size_t)k * 64 + g];
#pragma unroll
      for (int nd = 0; nd < 8; nd++)
        acc[nd] += h[(size_t)(n0 + nd) * 4608 + pm * 256 + k] * wv;
    }
#pragma unroll
    for (int nd = 0; nd < 8; nd++) {
      int n = n0 + nd;
      size_t idx = ((size_t)n * 18 + pm) * 64 + g;
      out[idx] += c[(size_t)n * 1664 + 1280 + (p * 3 + dm) * 64 + g] * acc[nd];
    }
  }
}

// ---------------- workspace layout (bytes) ----------------
#define OFF_C 0UL                    // 6000*1664*4 = 39,936,000
#define OFF_XPRE 39936000UL          // 27,648,000  (reused as x_pre2)
#define OFF_K 67584000UL             // 27,648,000  (reused as attn_out)
#define OFF_Q 95232000UL             // 27,648,000
#define OFF_V 122880000UL            // 27,648,000
#define OFF_SBUF 150528000UL         // 1,536,000 (inside later h region; done early)
#define OFF_H 95232000UL             // 110,592,000 (overlays q,v,sbuf — all dead by then)
#define OFF_LOGITS 205824000UL       // 1,152,000
#define OFF_LMAX 206976000UL         // 96,000
#define OFF_DENOM 207072000UL        // 96,000
#define OFF_CNT 207168000UL          // 24,000
#define OFF_CUTSUM 207192000UL       // 24,000
#define WS_NEEDED 207216000UL

extern "C" void kernel_launch(void* const* d_in, const int* in_sizes, int n_in,
                              void* d_out, int out_size, void* d_ws, size_t ws_size,
                              hipStream_t stream) {
  const float* f_nodes = (const float*)d_in[0];
  const float* f_edges = (const float*)d_in[1];
  const float* f_time = (const float*)d_in[2];
  const float* cutoff = (const float*)d_in[3];
  const float* ln_s = (const float*)d_in[4];
  const float* ln_b = (const float*)d_in[5];
  const float* W_c = (const float*)d_in[6];
  const float* b_c = (const float*)d_in[7];
  const float* Wq = (const float*)d_in[8];
  const float* Wk = (const float*)d_in[9];
  const float* Wv = (const float*)d_in[10];
  const float* Wo = (const float*)d_in[11];
  const float* We_qk = (const float*)d_in[12];
  const float* We_v = (const float*)d_in[13];
  const float* W1 = (const float*)d_in[14];
  const float* W2 = (const float*)d_in[15];
  const int* src_idx = (const int*)d_in[16];
  const int* dst_idx = (const int*)d_in[17];
  float* out = (float*)d_out;
  char* ws = (char*)d_ws;
  if (ws_size < WS_NEEDED) return;  // insufficient scratch; would show as poison absmax

  float* c = (float*)(ws + OFF_C);
  float* xpre = (float*)(ws + OFF_XPRE);
  float* kbuf = (float*)(ws + OFF_K);
  float* qbuf = (float*)(ws + OFF_Q);
  float* vbuf = (float*)(ws + OFF_V);
  float* sbuf = (float*)(ws + OFF_SBUF);
  float* hbuf = (float*)(ws + OFF_H);
  float* logits = (float*)(ws + OFF_LOGITS);
  unsigned* lmax = (unsigned*)(ws + OFF_LMAX);
  float* denom = (float*)(ws + OFF_DENOM);
  float* cnt = (float*)(ws + OFF_CNT);
  float* cutsum = (float*)(ws + OFF_CUTSUM);
  float* attn_out = kbuf;  // reuse: k dead after k_logits

  // zero lmax/denom/cnt/cutsum (contiguous)
  hipMemsetAsync(ws + OFF_LMAX, 0, 240000, stream);

  k_ln_t<<<1500, 256, 0, stream>>>(f_time, ln_s, ln_b, sbuf);
  k_cond_mm<<<750, 256, 0, stream>>>(sbuf, W_c, b_c, c);
  k_lnmod<<<3000, 256, 0, stream>>>(f_nodes, c, xpre, 0, 384);

  dim3 g94(94, 18);
  k_rowmat<<<g94, 256, 0, stream>>>(xpre, Wq, qbuf);
  k_rowmat<<<g94, 256, 0, stream>>>(xpre, Wk, kbuf);
  k_rowmat<<<g94, 256, 0, stream>>>(xpre, Wv, vbuf);

  k_logits<<<1024, 256, 0, stream>>>(f_edges, We_qk, qbuf, kbuf, src_idx, dst_idx,
                                     cutoff, logits, lmax, cnt, cutsum);
  // k dead now; zero it for attention accumulation
  hipMemsetAsync(ws + OFF_K, 0, 27648000, stream);
  k_expw<<<1125, 256, 0, stream>>>(logits, lmax, dst_idx, cutoff, denom);
  k_agg<<<1024, 256, 0, stream>>>(f_edges, We_v, vbuf, src_idx, dst_idx, logits,
                                  denom, attn_out);
  k_wo_post<<<g94, 256, 0, stream>>>(attn_out, Wo, xpre, f_nodes, c, cnt, cutsum, out);

  k_lnmod<<<3000, 256, 0, stream>>>(out, c, xpre, 832, 1216);  // x_pre2 (buffer reuse)
  k_mlp1<<<750, 256, 0, stream>>>(xpre, W1, hbuf);
  k_mlp2<<<750, 256, 0, stream>>>(hbuf, W2, c, out);
}